// Round 2
// baseline (210.596 us; speedup 1.0000x reference)
//
#include <hip/hip_runtime.h>
#include <stdint.h>

// B=4, S=1024, E=1024, H=16, dh=64
// ws layout (shorts): Xbf/Obf @0 (12.58M), Wqb @12582912 (1M), Wob @13631488 (1M),
//                     qkv @14680064 (12.58M: Q [B][H][S][64], K same +4M, V^T [B][H][64][S] +8M)

typedef __attribute__((ext_vector_type(8))) short bf16x8;
typedef __attribute__((ext_vector_type(4))) float f32x4;
typedef __attribute__((ext_vector_type(4))) short short4v;

#define GLOAD_LDS(gp, lp)                                                      \
  __builtin_amdgcn_global_load_lds(                                            \
      (__attribute__((address_space(1))) void*)(gp),                           \
      (__attribute__((address_space(3))) void*)(lp), 16, 0, 0)

__device__ __forceinline__ unsigned short f2bf(float f) {
  union { float f; unsigned u; } v; v.f = f;
  unsigned r = v.u + 0x7FFFu + ((v.u >> 16) & 1u);
  return (unsigned short)(r >> 16);
}

// ---------- fp32 -> bf16 convert, up to 3 sources in one launch ------------
template<int SHIFT>
__global__ void cvt3_kernel(const float* __restrict__ s0, const float* __restrict__ s1,
                            const float* __restrict__ s2, short* __restrict__ dst) {
  int i = blockIdx.x * blockDim.x + threadIdx.x;
  int which = i >> SHIFT;
  int j = i & ((1 << SHIFT) - 1);
  const float* src = (which == 0) ? s0 : (which == 1) ? s1 : s2;
  float4 f = reinterpret_cast<const float4*>(src)[j];
  short4v o;
  o.x = (short)f2bf(f.x); o.y = (short)f2bf(f.y);
  o.z = (short)f2bf(f.z); o.w = (short)f2bf(f.w);
  reinterpret_cast<short4v*>(dst)[i] = o;
}

// ---------------- bf16 GEMM  C = A[M,1024] * W[1024,1024]^T + bias ---------
// EPI 0: proj -> scatter to qkv (Q,K row-major per head; V transposed) [bf16]
// EPI 1: final -> fp32 d_out
template<int EPI>
__global__ __launch_bounds__(256, 2)
void gemm_bt(const short* __restrict__ A, const short* __restrict__ Bw,
             const float* __restrict__ bias,
             short* __restrict__ qkv, float* __restrict__ outf)
{
  __shared__ short As[128 * 64];
  __shared__ short Bs[128 * 64];
  const int tid  = threadIdx.x;
  const int lane = tid & 63;
  const int g    = lane >> 4;     // 16-lane group 0..3
  const int r7   = lane & 7;
  const int w    = tid >> 6;      // wave 0..3
  const int wm   = w >> 1, wn = w & 1;

  // XCD-aware bijective swizzle (gridDim.x==8, nwg%8==0)
  const int orig = blockIdx.y * 8 + blockIdx.x;
  const int cpx  = (gridDim.x * gridDim.y) >> 3;
  const int t    = (orig & 7) * cpx + (orig >> 3);
  const int m0   = (t >> 3) * 128, n0 = (t & 7) * 128;

  f32x4 acc[4][4] = {};

  for (int k0 = 0; k0 < 1024; k0 += 64) {
    // stage A,B tiles [128][64] bf16; XOR-swizzled via pre-swizzled global src
#pragma unroll
    for (int c = 0; c < 4; c++) {
      int L   = c * 256 + tid;
      int row = L >> 3;
      int col = ((L & 7) ^ (row & 7)) * 8;
      GLOAD_LDS(A  + (m0 + row) * 1024 + k0 + col, As + L * 8);
      GLOAD_LDS(Bw + (n0 + row) * 1024 + k0 + col, Bs + L * 8);
    }
    __syncthreads();
#pragma unroll
    for (int kk = 0; kk < 2; kk++) {
      bf16x8 av[4], bv[4];
#pragma unroll
      for (int mi = 0; mi < 4; mi++) {
        int row = wm * 64 + mi * 16 + (lane & 15);
        av[mi] = *(const bf16x8*)&As[row * 64 + (((kk * 4 + g) ^ r7) * 8)];
      }
#pragma unroll
      for (int ni = 0; ni < 4; ni++) {
        int row = wn * 64 + ni * 16 + (lane & 15);
        bv[ni] = *(const bf16x8*)&Bs[row * 64 + (((kk * 4 + g) ^ r7) * 8)];
      }
#pragma unroll
      for (int mi = 0; mi < 4; mi++)
#pragma unroll
        for (int ni = 0; ni < 4; ni++)
          acc[mi][ni] = __builtin_amdgcn_mfma_f32_16x16x32_bf16(av[mi], bv[ni], acc[mi][ni], 0, 0, 0);
    }
    __syncthreads();
  }

  if (EPI == 0) {
    const int inp = m0 >> 12;  // 0=q,1=k,2=v (block never straddles inputs)
#pragma unroll
    for (int mi = 0; mi < 4; mi++) {
#pragma unroll
      for (int ni = 0; ni < 4; ni++) {
        const int coll = n0 + wn * 64 + ni * 16 + (lane & 15);
        const float bv = bias[coll];
        const int rbase = m0 + wm * 64 + mi * 16 + (lane >> 4) * 4;
        const int hh = coll >> 6, d = coll & 63;
        if (inp < 2) {
#pragma unroll
          for (int j = 0; j < 4; j++) {
            int rowl = rbase + j;
            int bb = (rowl >> 10) & 3, s = rowl & 1023;
            qkv[(((inp * 4 + bb) * 16 + hh) * 1024 + s) * 64 + d] =
                (short)f2bf(acc[mi][ni][j] + bv);
          }
        } else {
          int bb = (rbase >> 10) & 3, s0 = rbase & 1023;
          short4v o;
          o.x = (short)f2bf(acc[mi][ni][0] + bv);
          o.y = (short)f2bf(acc[mi][ni][1] + bv);
          o.z = (short)f2bf(acc[mi][ni][2] + bv);
          o.w = (short)f2bf(acc[mi][ni][3] + bv);
          *(short4v*)&qkv[8 * 1024 * 1024 + ((bb * 16 + hh) * 64 + d) * 1024 + s0] = o;
        }
      }
    }
  } else {
#pragma unroll
    for (int mi = 0; mi < 4; mi++) {
#pragma unroll
      for (int ni = 0; ni < 4; ni++) {
        const int coll = n0 + wn * 64 + ni * 16 + (lane & 15);
        const float bv = bias[coll];
        const int rbase = m0 + wm * 64 + mi * 16 + (lane >> 4) * 4;
#pragma unroll
        for (int j = 0; j < 4; j++)
          outf[(rbase + j) * 1024 + coll] = acc[mi][ni][j] + bv;
      }
    }
  }
}

// ---------------- flash attention: 1 block = (b,h, 64 q-rows) --------------
__global__ __launch_bounds__(256, 2)
void attn_kernel(const short* __restrict__ qkv, short* __restrict__ O)
{
  __shared__ short Ks[64 * 64];
  __shared__ short VTs[64 * 64];
  __shared__ short QPs[64 * 64];   // Q tile during hoist, then P tile

  const int tid  = threadIdx.x;
  const int lane = tid & 63;
  const int g    = lane >> 4, r7 = lane & 7;
  const int w    = tid >> 6;

  // XCD swizzle: each XCD owns 8 contiguous (b,h) K/V sets (2 MB -> L2-fits)
  const int t   = (blockIdx.x & 7) * 128 + (blockIdx.x >> 3);
  const int qt  = t & 15, hh = (t >> 4) & 15, bb = t >> 8;
  const int q0  = qt * 64;

  const short* Qg = qkv + (bb * 16 + hh) * 1024 * 64;                     // [1024][64]
  const short* Kg = qkv + 4 * 1024 * 1024 + (bb * 16 + hh) * 1024 * 64;   // [1024][64]
  const short* Vg = qkv + 8 * 1024 * 1024 + (bb * 16 + hh) * 64 * 1024;   // [64][1024]

  // stage Q tile [64][64] (swizzled source), hoist wave's Q fragment to regs
#pragma unroll
  for (int c = 0; c < 2; c++) {
    int L = c * 256 + tid;
    int row = L >> 3;
    int col = ((L & 7) ^ (row & 7)) * 8;
    GLOAD_LDS(Qg + (q0 + row) * 64 + col, QPs + L * 8);
  }
  __syncthreads();  // drains vmcnt -> Q tile resident
  bf16x8 qf[2];
  {
    const int qrow = w * 16 + (lane & 15);
    qf[0] = *(const bf16x8*)&QPs[qrow * 64 + ((g ^ r7) * 8)];
    qf[1] = *(const bf16x8*)&QPs[qrow * 64 + (((4 + g) ^ r7) * 8)];
  }

  float m_run[4], l_run[4];
  f32x4 acc_o[4] = {};
#pragma unroll
  for (int j = 0; j < 4; j++) { m_run[j] = -1e30f; l_run[j] = 0.0f; }

  for (int kt = 0; kt < 16; kt++) {
    __syncthreads();  // prev tile's LDS reads done (kt=0: qf reads complete via lgkmcnt)
#pragma unroll
    for (int c = 0; c < 2; c++) {
      int L = c * 256 + tid;
      int row = L >> 3;
      int col = ((L & 7) ^ (row & 7)) * 8;
      GLOAD_LDS(Kg + (kt * 64 + row) * 64 + col, Ks + L * 8);
      GLOAD_LDS(Vg + row * 1024 + kt * 64 + col, VTs + L * 8);
    }
    __syncthreads();

    // ---- QK^T: wave computes 16 q-rows x 64 k-cols ----
    f32x4 sa[4] = {};
#pragma unroll
    for (int kk = 0; kk < 2; kk++) {
#pragma unroll
      for (int ni = 0; ni < 4; ni++) {
        int krow = ni * 16 + (lane & 15);
        bf16x8 kf = *(const bf16x8*)&Ks[krow * 64 + (((kk * 4 + g) ^ r7) * 8)];
        sa[ni] = __builtin_amdgcn_mfma_f32_16x16x32_bf16(qf[kk], kf, sa[ni], 0, 0, 0);
      }
    }
    // ---- online softmax (quarter-wave g owns rows 4g..4g+3) ----
    float mt[4];
#pragma unroll
    for (int j = 0; j < 4; j++)
      mt[j] = fmaxf(fmaxf(sa[0][j], sa[1][j]), fmaxf(sa[2][j], sa[3][j]));
#pragma unroll
    for (int off = 1; off < 16; off <<= 1)
#pragma unroll
      for (int j = 0; j < 4; j++)
        mt[j] = fmaxf(mt[j], __shfl_xor(mt[j], off));
    float alpha[4], rs[4];
#pragma unroll
    for (int j = 0; j < 4; j++) {
      float mn = fmaxf(m_run[j], mt[j] * 0.125f);
      alpha[j] = __expf(m_run[j] - mn);
      m_run[j] = mn;
      rs[j] = 0.0f;
    }
#pragma unroll
    for (int ni = 0; ni < 4; ni++) {
      int col = ni * 16 + (lane & 15);
#pragma unroll
      for (int j = 0; j < 4; j++) {
        int row = w * 16 + g * 4 + j;
        float p = __expf(sa[ni][j] * 0.125f - m_run[j]);
        rs[j] += p;
        QPs[row * 64 + (col ^ ((row & 7) << 3))] = (short)f2bf(p);
      }
    }
#pragma unroll
    for (int off = 1; off < 16; off <<= 1)
#pragma unroll
      for (int j = 0; j < 4; j++)
        rs[j] += __shfl_xor(rs[j], off);
#pragma unroll
    for (int j = 0; j < 4; j++)
      l_run[j] = l_run[j] * alpha[j] + rs[j];
#pragma unroll
    for (int di = 0; di < 4; di++)
#pragma unroll
      for (int j = 0; j < 4; j++)
        acc_o[di][j] *= alpha[j];
    // ---- PV: O[16q][64d] += P[16q][64k] * V[64k][64d] (V^T in LDS) ----
#pragma unroll
    for (int kk = 0; kk < 2; kk++) {
      int prow = w * 16 + (lane & 15);
      bf16x8 pf = *(const bf16x8*)&QPs[prow * 64 + (((kk * 4 + g) ^ r7) * 8)];
#pragma unroll
      for (int di = 0; di < 4; di++) {
        int vrow = di * 16 + (lane & 15);
        bf16x8 vf = *(const bf16x8*)&VTs[vrow * 64 + (((kk * 4 + g) ^ r7) * 8)];
        acc_o[di] = __builtin_amdgcn_mfma_f32_16x16x32_bf16(pf, vf, acc_o[di], 0, 0, 0);
      }
    }
  }

  // write O [b][s][h*64+d] bf16
#pragma unroll
  for (int di = 0; di < 4; di++) {
    int d = hh * 64 + di * 16 + (lane & 15);
#pragma unroll
    for (int j = 0; j < 4; j++) {
      int q = q0 + w * 16 + g * 4 + j;
      O[(bb * 1024 + q) * 1024 + d] = (short)f2bf(acc_o[di][j] / l_run[j]);
    }
  }
}

extern "C" void kernel_launch(void* const* d_in, const int* in_sizes, int n_in,
                              void* d_out, int out_size, void* d_ws, size_t ws_size,
                              hipStream_t stream)
{
  (void)in_sizes; (void)n_in; (void)out_size; (void)ws_size;
  const float* q    = (const float*)d_in[0];
  const float* k    = (const float*)d_in[1];
  const float* v    = (const float*)d_in[2];
  const float* Wq_w = (const float*)d_in[3];
  const float* Wq_b = (const float*)d_in[4];
  const float* Wo_w = (const float*)d_in[5];
  const float* Wo_b = (const float*)d_in[6];
  float* out = (float*)d_out;

  short* ws   = (short*)d_ws;
  short* Xbf  = ws;                 // [3*4096][1024] bf16 (q,k,v projected inputs)
  short* Obf  = ws;                 // aliases Xbf (dead after proj GEMM)
  short* Wqb  = ws + 12582912;
  short* Wob  = ws + 13631488;
  short* qkv  = ws + 14680064;

  cvt3_kernel<20><<<12288, 256, 0, stream>>>(q, k, v, Xbf);
  cvt3_kernel<18><<<2048, 256, 0, stream>>>(Wq_w, Wo_w, Wo_w, Wqb);  // Wqb then Wob (adjacent)

  dim3 gp(8, 96);   // N/128=8, M/128=96  (q,k,v batched: same Wq per reference bug)
  gemm_bt<0><<<gp, 256, 0, stream>>>(Xbf, Wqb, Wq_b, qkv, nullptr);

  attn_kernel<<<1024, 256, 0, stream>>>(qkv, Obf);

  dim3 gf(8, 32);
  gemm_bt<1><<<gf, 256, 0, stream>>>(Obf, Wob, Wo_b, nullptr, out);
}

// Round 4
// 209.328 us; speedup vs baseline: 1.0061x; 1.0061x over previous
//
#include <hip/hip_runtime.h>
#include <stdint.h>

// B=4, S=1024, E=1024, H=16, dh=64
// ws layout (shorts): Xbf/Obf @0 (12.58M), Wqb @12582912 (1M), Wob @13631488 (1M),
//                     qkv @14680064 (12.58M: Q [B][H][S][64], K same +4M, V^T [B][H][64][S] +8M)

typedef __attribute__((ext_vector_type(8))) short bf16x8;
typedef __attribute__((ext_vector_type(4))) float f32x4;
typedef __attribute__((ext_vector_type(4))) short short4v;

#define GLOAD_LDS(gp, lp)                                                      \
  __builtin_amdgcn_global_load_lds(                                            \
      (__attribute__((address_space(1))) void*)(gp),                           \
      (__attribute__((address_space(3))) void*)(lp), 16, 0, 0)

__device__ __forceinline__ unsigned short f2bf(float f) {
  union { float f; unsigned u; } v; v.f = f;
  unsigned r = v.u + 0x7FFFu + ((v.u >> 16) & 1u);
  return (unsigned short)(r >> 16);
}

// ---------- fp32 -> bf16 convert: all 5 tensors in ONE launch --------------
// dst quad i: [0,1M)=q, [1M,2M)=k, [2M,3M)=v, [3M,3.25M)=Wq, [3.25M,3.5M)=Wo
// (Xbf, Wqb, Wob are contiguous in ws, so dst index == i uniformly)
__global__ void cvt_all(const float* __restrict__ q, const float* __restrict__ k,
                        const float* __restrict__ v, const float* __restrict__ wq,
                        const float* __restrict__ wo, short* __restrict__ dst) {
  int i = blockIdx.x * 256 + threadIdx.x;
  const float* src; int j;
  if (i < 1048576)      { src = q;  j = i; }
  else if (i < 2097152) { src = k;  j = i - 1048576; }
  else if (i < 3145728) { src = v;  j = i - 2097152; }
  else if (i < 3407872) { src = wq; j = i - 3145728; }
  else                  { src = wo; j = i - 3407872; }
  float4 f = reinterpret_cast<const float4*>(src)[j];
  short4v o;
  o.x = (short)f2bf(f.x); o.y = (short)f2bf(f.y);
  o.z = (short)f2bf(f.z); o.w = (short)f2bf(f.w);
  reinterpret_cast<short4v*>(dst)[i] = o;
}

// ---------------- bf16 GEMM  C = A[M,1024] * W[1024,1024]^T + bias ---------
// EPI 0: proj -> scatter to qkv (Q,K row-major per head; V transposed) [bf16]
// EPI 1: final -> fp32 d_out
template<int EPI>
__global__ __launch_bounds__(256, 2)
void gemm_bt(const short* __restrict__ A, const short* __restrict__ Bw,
             const float* __restrict__ bias,
             short* __restrict__ qkv, float* __restrict__ outf)
{
  __shared__ short As[128 * 64];
  __shared__ short Bs[128 * 64];
  const int tid  = threadIdx.x;
  const int lane = tid & 63;
  const int g    = lane >> 4;     // 16-lane group 0..3
  const int r7   = lane & 7;
  const int w    = tid >> 6;      // wave 0..3
  const int wm   = w >> 1, wn = w & 1;

  // XCD-aware bijective swizzle (nwg%8==0)
  const int orig = blockIdx.y * 8 + blockIdx.x;
  const int cpx  = (gridDim.x * gridDim.y) >> 3;
  const int t    = (orig & 7) * cpx + (orig >> 3);
  const int m0   = (t >> 3) * 128, n0 = (t & 7) * 128;

  f32x4 acc[4][4] = {};

  for (int k0 = 0; k0 < 1024; k0 += 64) {
#pragma unroll
    for (int c = 0; c < 4; c++) {
      int L   = c * 256 + tid;
      int row = L >> 3;
      int col = ((L & 7) ^ (row & 7)) * 8;
      GLOAD_LDS(A  + (m0 + row) * 1024 + k0 + col, As + L * 8);
      GLOAD_LDS(Bw + (n0 + row) * 1024 + k0 + col, Bs + L * 8);
    }
    __syncthreads();
#pragma unroll
    for (int kk = 0; kk < 2; kk++) {
      bf16x8 av[4], bv[4];
#pragma unroll
      for (int mi = 0; mi < 4; mi++) {
        int row = wm * 64 + mi * 16 + (lane & 15);
        av[mi] = *(const bf16x8*)&As[row * 64 + (((kk * 4 + g) ^ r7) * 8)];
      }
#pragma unroll
      for (int ni = 0; ni < 4; ni++) {
        int row = wn * 64 + ni * 16 + (lane & 15);
        bv[ni] = *(const bf16x8*)&Bs[row * 64 + (((kk * 4 + g) ^ r7) * 8)];
      }
#pragma unroll
      for (int mi = 0; mi < 4; mi++)
#pragma unroll
        for (int ni = 0; ni < 4; ni++)
          acc[mi][ni] = __builtin_amdgcn_mfma_f32_16x16x32_bf16(av[mi], bv[ni], acc[mi][ni], 0, 0, 0);
    }
    __syncthreads();
  }

  if (EPI == 0) {
    const int inp = m0 >> 12;  // 0=q,1=k,2=v (block never straddles inputs)
#pragma unroll
    for (int mi = 0; mi < 4; mi++) {
#pragma unroll
      for (int ni = 0; ni < 4; ni++) {
        const int coll = n0 + wn * 64 + ni * 16 + (lane & 15);
        const float bv = bias[coll];
        const int rbase = m0 + wm * 64 + mi * 16 + (lane >> 4) * 4;
        const int hh = coll >> 6, d = coll & 63;
        if (inp < 2) {
#pragma unroll
          for (int j = 0; j < 4; j++) {
            int rowl = rbase + j;
            int bb = (rowl >> 10) & 3, s = rowl & 1023;
            qkv[(((inp * 4 + bb) * 16 + hh) * 1024 + s) * 64 + d] =
                (short)f2bf(acc[mi][ni][j] + bv);
          }
        } else {
          int bb = (rbase >> 10) & 3, s0 = rbase & 1023;
          short4v o;
          o.x = (short)f2bf(acc[mi][ni][0] + bv);
          o.y = (short)f2bf(acc[mi][ni][1] + bv);
          o.z = (short)f2bf(acc[mi][ni][2] + bv);
          o.w = (short)f2bf(acc[mi][ni][3] + bv);
          *(short4v*)&qkv[8 * 1024 * 1024 + ((bb * 16 + hh) * 64 + d) * 1024 + s0] = o;
        }
      }
    }
  } else {
#pragma unroll
    for (int mi = 0; mi < 4; mi++) {
#pragma unroll
      for (int ni = 0; ni < 4; ni++) {
        const int coll = n0 + wn * 64 + ni * 16 + (lane & 15);
        const float bv = bias[coll];
        const int rbase = m0 + wm * 64 + mi * 16 + (lane >> 4) * 4;
#pragma unroll
        for (int j = 0; j < 4; j++)
          outf[(rbase + j) * 1024 + coll] = acc[mi][ni][j] + bv;
      }
    }
  }
}

// ------- flash attention, 2-phase double-buffered: 1 block = (b,h,64 q) ----
__global__ __launch_bounds__(256, 2)
void attn_kernel(const short* __restrict__ qkv, short* __restrict__ O)
{
  __shared__ short Ks[2][64 * 64];
  __shared__ short VTs[2][64 * 64];
  __shared__ short QPs[64 * 64];   // Q tile during hoist, then per-wave P rows

  const int tid  = threadIdx.x;
  const int lane = tid & 63;
  const int g    = lane >> 4, r7 = lane & 7;
  const int w    = tid >> 6;

  // XCD swizzle: each XCD owns 8 contiguous (b,h) K/V sets (2 MB -> L2-fits)
  const int t   = (blockIdx.x & 7) * 128 + (blockIdx.x >> 3);
  const int qt  = t & 15, hh = (t >> 4) & 15, bb = t >> 8;
  const int q0  = qt * 64;

  const short* Qg = qkv + (bb * 16 + hh) * 1024 * 64;                     // [1024][64]
  const short* Kg = qkv + 4 * 1024 * 1024 + (bb * 16 + hh) * 1024 * 64;   // [1024][64]
  const short* Vg = qkv + 8 * 1024 * 1024 + (bb * 16 + hh) * 64 * 1024;   // [64][1024]

  // prologue: stage Q tile + K/V tile 0 (all swizzled-source, linear LDS dest)
#pragma unroll
  for (int c = 0; c < 2; c++) {
    int L = c * 256 + tid;
    int row = L >> 3;
    int col = ((L & 7) ^ (row & 7)) * 8;
    GLOAD_LDS(Qg + (q0 + row) * 64 + col, QPs + L * 8);
    GLOAD_LDS(Kg + row * 64 + col,        &Ks[0][L * 8]);
    GLOAD_LDS(Vg + row * 1024 + col,      &VTs[0][L * 8]);
  }
  __syncthreads();
  bf16x8 qf[2];
  {
    const int qrow = w * 16 + (lane & 15);
    qf[0] = *(const bf16x8*)&QPs[qrow * 64 + ((g ^ r7) * 8)];
    qf[1] = *(const bf16x8*)&QPs[qrow * 64 + (((4 + g) ^ r7) * 8)];
  }

  const float SC = 0.125f * 1.44269504f;   // 1/sqrt(dh) * log2(e)
  float m_run[4], l_run[4];
  f32x4 acc_o[4] = {};
#pragma unroll
  for (int j = 0; j < 4; j++) { m_run[j] = -1e30f; l_run[j] = 0.0f; }

  int cur = 0;
  for (int kt = 0; kt < 16; kt++) {
    // issue next tile's stage first — drains under this tile's compute
    if (kt < 15) {
#pragma unroll
      for (int c = 0; c < 2; c++) {
        int L = c * 256 + tid;
        int row = L >> 3;
        int col = ((L & 7) ^ (row & 7)) * 8;
        GLOAD_LDS(Kg + ((kt + 1) * 64 + row) * 64 + col, &Ks[cur ^ 1][L * 8]);
        GLOAD_LDS(Vg + row * 1024 + (kt + 1) * 64 + col, &VTs[cur ^ 1][L * 8]);
      }
    }

    // ---- QK^T: wave computes 16 q-rows x 64 k-cols ----
    f32x4 sa[4] = {};
#pragma unroll
    for (int kk = 0; kk < 2; kk++) {
#pragma unroll
      for (int ni = 0; ni < 4; ni++) {
        int krow = ni * 16 + (lane & 15);
        bf16x8 kf = *(const bf16x8*)&Ks[cur][krow * 64 + (((kk * 4 + g) ^ r7) * 8)];
        sa[ni] = __builtin_amdgcn_mfma_f32_16x16x32_bf16(qf[kk], kf, sa[ni], 0, 0, 0);
      }
    }
    // ---- online softmax in exp2 domain (group g owns rows 4g..4g+3) ----
    float mt[4];
#pragma unroll
    for (int j = 0; j < 4; j++)
      mt[j] = fmaxf(fmaxf(sa[0][j], sa[1][j]), fmaxf(sa[2][j], sa[3][j]));
#pragma unroll
    for (int off = 1; off < 16; off <<= 1)
#pragma unroll
      for (int j = 0; j < 4; j++)
        mt[j] = fmaxf(mt[j], __shfl_xor(mt[j], off));
    float alpha[4], rs[4];
#pragma unroll
    for (int j = 0; j < 4; j++) {
      float mn = fmaxf(m_run[j], mt[j] * SC);
      alpha[j] = __builtin_amdgcn_exp2f(m_run[j] - mn);
      m_run[j] = mn;
      rs[j] = 0.0f;
    }
#pragma unroll
    for (int ni = 0; ni < 4; ni++) {
      int col = ni * 16 + (lane & 15);
#pragma unroll
      for (int j = 0; j < 4; j++) {
        int row = w * 16 + g * 4 + j;
        float p = __builtin_amdgcn_exp2f(sa[ni][j] * SC - m_run[j]);
        rs[j] += p;
        QPs[row * 64 + (col ^ ((row & 7) << 3))] = (short)f2bf(p);
      }
    }
#pragma unroll
    for (int off = 1; off < 16; off <<= 1)
#pragma unroll
      for (int j = 0; j < 4; j++)
        rs[j] += __shfl_xor(rs[j], off);
#pragma unroll
    for (int j = 0; j < 4; j++)
      l_run[j] = l_run[j] * alpha[j] + rs[j];
#pragma unroll
    for (int di = 0; di < 4; di++)
#pragma unroll
      for (int j = 0; j < 4; j++)
        acc_o[di][j] *= alpha[j];
    // ---- PV: O[16q][64d] += P[16q][64k] * V[64k][64d] (V^T in LDS) ----
#pragma unroll
    for (int kk = 0; kk < 2; kk++) {
      int prow = w * 16 + (lane & 15);
      bf16x8 pf = *(const bf16x8*)&QPs[prow * 64 + (((kk * 4 + g) ^ r7) * 8)];
#pragma unroll
      for (int di = 0; di < 4; di++) {
        int vrow = di * 16 + (lane & 15);
        bf16x8 vf = *(const bf16x8*)&VTs[cur][vrow * 64 + (((kk * 4 + g) ^ r7) * 8)];
        acc_o[di] = __builtin_amdgcn_mfma_f32_16x16x32_bf16(pf, vf, acc_o[di], 0, 0, 0);
      }
    }
    __syncthreads();   // drains vmcnt: next tile staged; buf[cur] free for reuse
    cur ^= 1;
  }

  // write O [b][s][h*64+d] bf16
#pragma unroll
  for (int di = 0; di < 4; di++) {
    int d = hh * 64 + di * 16 + (lane & 15);
#pragma unroll
    for (int j = 0; j < 4; j++) {
      int q = q0 + w * 16 + g * 4 + j;
      O[(bb * 1024 + q) * 1024 + d] = (short)f2bf(acc_o[di][j] / l_run[j]);
    }
  }
}

extern "C" void kernel_launch(void* const* d_in, const int* in_sizes, int n_in,
                              void* d_out, int out_size, void* d_ws, size_t ws_size,
                              hipStream_t stream)
{
  (void)in_sizes; (void)n_in; (void)out_size; (void)ws_size;
  const float* q    = (const float*)d_in[0];
  const float* k    = (const float*)d_in[1];
  const float* v    = (const float*)d_in[2];
  const float* Wq_w = (const float*)d_in[3];
  const float* Wq_b = (const float*)d_in[4];
  const float* Wo_w = (const float*)d_in[5];
  const float* Wo_b = (const float*)d_in[6];
  float* out = (float*)d_out;

  short* ws   = (short*)d_ws;
  short* Xbf  = ws;                 // [3*4096][1024] bf16 (q,k,v inputs; Wqb/Wob follow)
  short* Obf  = ws;                 // aliases Xbf (dead after proj GEMM)
  short* Wqb  = ws + 12582912;
  short* Wob  = ws + 13631488;
  short* qkv  = ws + 14680064;

  cvt_all<<<14336, 256, 0, stream>>>(q, k, v, Wq_w, Wo_w, ws);

  dim3 gp(8, 96);   // N/128=8, M/128=96  (q,k,v batched: same Wq per reference bug)
  gemm_bt<0><<<gp, 256, 0, stream>>>(Xbf, Wqb, Wq_b, qkv, nullptr);

  attn_kernel<<<1024, 256, 0, stream>>>(qkv, Obf);

  dim3 gf(8, 32);
  gemm_bt<1><<<gf, 256, 0, stream>>>(Obf, Wob, Wo_b, nullptr, out);
}

// Round 5
// 206.489 us; speedup vs baseline: 1.0199x; 1.0137x over previous
//
#include <hip/hip_runtime.h>
#include <stdint.h>

// B=4, S=1024, E=1024, H=16, dh=64
// ws layout (shorts): Xbf/Obf @0 (12.58M), Wqb @12582912 (1M), Wob @13631488 (1M),
//                     qkv @14680064 (12.58M: Q [B][H][S][64], K same +4M, V^T [B][H][64][S] +8M)

typedef __attribute__((ext_vector_type(8))) short bf16x8;
typedef __attribute__((ext_vector_type(4))) float f32x4;
typedef __attribute__((ext_vector_type(4))) short short4v;

#define GLOAD_LDS(gp, lp)                                                      \
  __builtin_amdgcn_global_load_lds(                                            \
      (__attribute__((address_space(1))) void*)(gp),                           \
      (__attribute__((address_space(3))) void*)(lp), 16, 0, 0)

__device__ __forceinline__ unsigned short f2bf(float f) {
  union { float f; unsigned u; } v; v.f = f;
  unsigned r = v.u + 0x7FFFu + ((v.u >> 16) & 1u);
  return (unsigned short)(r >> 16);
}

// DPP row_ror:N within each 16-lane row — VALU cross-lane, no DS pipe.
template<int CTRL>
__device__ __forceinline__ float dpp_rr(float x) {
  union { float f; int i; } a, r;
  a.f = x;
  r.i = __builtin_amdgcn_update_dpp(0, a.i, CTRL, 0xf, 0xf, false);
  return r.f;
}
// all-reduce max/sum over the 16-lane row (row_ror 1,2,4,8)
__device__ __forceinline__ float rowmax16(float x) {
  x = fmaxf(x, dpp_rr<0x121>(x));
  x = fmaxf(x, dpp_rr<0x122>(x));
  x = fmaxf(x, dpp_rr<0x124>(x));
  x = fmaxf(x, dpp_rr<0x128>(x));
  return x;
}
__device__ __forceinline__ float rowsum16(float x) {
  x += dpp_rr<0x121>(x);
  x += dpp_rr<0x122>(x);
  x += dpp_rr<0x124>(x);
  x += dpp_rr<0x128>(x);
  return x;
}

// ---------- fp32 -> bf16 convert: all 5 tensors in ONE launch --------------
__global__ void cvt_all(const float* __restrict__ q, const float* __restrict__ k,
                        const float* __restrict__ v, const float* __restrict__ wq,
                        const float* __restrict__ wo, short* __restrict__ dst) {
  int i = blockIdx.x * 256 + threadIdx.x;
  const float* src; int j;
  if (i < 1048576)      { src = q;  j = i; }
  else if (i < 2097152) { src = k;  j = i - 1048576; }
  else if (i < 3145728) { src = v;  j = i - 2097152; }
  else if (i < 3407872) { src = wq; j = i - 3145728; }
  else                  { src = wo; j = i - 3407872; }
  float4 f = reinterpret_cast<const float4*>(src)[j];
  short4v o;
  o.x = (short)f2bf(f.x); o.y = (short)f2bf(f.y);
  o.z = (short)f2bf(f.z); o.w = (short)f2bf(f.w);
  reinterpret_cast<short4v*>(dst)[i] = o;
}

// ---------------- bf16 GEMM  C = A[M,1024] * W[1024,1024]^T + bias ---------
template<int EPI>
__global__ __launch_bounds__(256, 2)
void gemm_bt(const short* __restrict__ A, const short* __restrict__ Bw,
             const float* __restrict__ bias,
             short* __restrict__ qkv, float* __restrict__ outf)
{
  __shared__ short As[128 * 64];
  __shared__ short Bs[128 * 64];
  const int tid  = threadIdx.x;
  const int lane = tid & 63;
  const int g    = lane >> 4;     // 16-lane group 0..3
  const int r7   = lane & 7;
  const int w    = tid >> 6;      // wave 0..3
  const int wm   = w >> 1, wn = w & 1;

  // XCD-aware bijective swizzle (nwg%8==0)
  const int orig = blockIdx.y * 8 + blockIdx.x;
  const int cpx  = (gridDim.x * gridDim.y) >> 3;
  const int t    = (orig & 7) * cpx + (orig >> 3);
  const int m0   = (t >> 3) * 128, n0 = (t & 7) * 128;

  f32x4 acc[4][4] = {};

  for (int k0 = 0; k0 < 1024; k0 += 64) {
#pragma unroll
    for (int c = 0; c < 4; c++) {
      int L   = c * 256 + tid;
      int row = L >> 3;
      int col = ((L & 7) ^ (row & 7)) * 8;
      GLOAD_LDS(A  + (m0 + row) * 1024 + k0 + col, As + L * 8);
      GLOAD_LDS(Bw + (n0 + row) * 1024 + k0 + col, Bs + L * 8);
    }
    __syncthreads();
#pragma unroll
    for (int kk = 0; kk < 2; kk++) {
      bf16x8 av[4], bv[4];
#pragma unroll
      for (int mi = 0; mi < 4; mi++) {
        int row = wm * 64 + mi * 16 + (lane & 15);
        av[mi] = *(const bf16x8*)&As[row * 64 + (((kk * 4 + g) ^ r7) * 8)];
      }
#pragma unroll
      for (int ni = 0; ni < 4; ni++) {
        int row = wn * 64 + ni * 16 + (lane & 15);
        bv[ni] = *(const bf16x8*)&Bs[row * 64 + (((kk * 4 + g) ^ r7) * 8)];
      }
#pragma unroll
      for (int mi = 0; mi < 4; mi++)
#pragma unroll
        for (int ni = 0; ni < 4; ni++)
          acc[mi][ni] = __builtin_amdgcn_mfma_f32_16x16x32_bf16(av[mi], bv[ni], acc[mi][ni], 0, 0, 0);
    }
    __syncthreads();
  }

  if (EPI == 0) {
    const int inp = m0 >> 12;  // 0=q,1=k,2=v (block never straddles inputs)
#pragma unroll
    for (int mi = 0; mi < 4; mi++) {
#pragma unroll
      for (int ni = 0; ni < 4; ni++) {
        const int coll = n0 + wn * 64 + ni * 16 + (lane & 15);
        const float bv = bias[coll];
        const int rbase = m0 + wm * 64 + mi * 16 + (lane >> 4) * 4;
        const int hh = coll >> 6, d = coll & 63;
        if (inp < 2) {
#pragma unroll
          for (int j = 0; j < 4; j++) {
            int rowl = rbase + j;
            int bb = (rowl >> 10) & 3, s = rowl & 1023;
            qkv[(((inp * 4 + bb) * 16 + hh) * 1024 + s) * 64 + d] =
                (short)f2bf(acc[mi][ni][j] + bv);
          }
        } else {
          int bb = (rbase >> 10) & 3, s0 = rbase & 1023;
          short4v o;
          o.x = (short)f2bf(acc[mi][ni][0] + bv);
          o.y = (short)f2bf(acc[mi][ni][1] + bv);
          o.z = (short)f2bf(acc[mi][ni][2] + bv);
          o.w = (short)f2bf(acc[mi][ni][3] + bv);
          *(short4v*)&qkv[8 * 1024 * 1024 + ((bb * 16 + hh) * 64 + d) * 1024 + s0] = o;
        }
      }
    }
  } else {
#pragma unroll
    for (int mi = 0; mi < 4; mi++) {
#pragma unroll
      for (int ni = 0; ni < 4; ni++) {
        const int coll = n0 + wn * 64 + ni * 16 + (lane & 15);
        const float bv = bias[coll];
        const int rbase = m0 + wm * 64 + mi * 16 + (lane >> 4) * 4;
#pragma unroll
        for (int j = 0; j < 4; j++)
          outf[(rbase + j) * 1024 + coll] = acc[mi][ni][j] + bv;
      }
    }
  }
}

// ------- flash attention, 2-phase double-buffered: 1 block = (b,h,64 q) ----
__global__ __launch_bounds__(256, 2)
void attn_kernel(const short* __restrict__ qkv, short* __restrict__ O)
{
  __shared__ short Ks[2][64 * 64];
  __shared__ short VTs[2][64 * 64];
  __shared__ short QPs[64 * 64];   // Q tile during hoist, then per-wave P rows

  const int tid  = threadIdx.x;
  const int lane = tid & 63;
  const int g    = lane >> 4, r7 = lane & 7;
  const int w    = tid >> 6;

  // XCD swizzle: each XCD owns 8 contiguous (b,h) K/V sets (2 MB -> L2-fits)
  const int t   = (blockIdx.x & 7) * 128 + (blockIdx.x >> 3);
  const int qt  = t & 15, hh = (t >> 4) & 15, bb = t >> 8;
  const int q0  = qt * 64;

  const short* Qg = qkv + (bb * 16 + hh) * 1024 * 64;                     // [1024][64]
  const short* Kg = qkv + 4 * 1024 * 1024 + (bb * 16 + hh) * 1024 * 64;   // [1024][64]
  const short* Vg = qkv + 8 * 1024 * 1024 + (bb * 16 + hh) * 64 * 1024;   // [64][1024]

  // prologue: stage Q tile + K/V tile 0 (swizzled source, linear LDS dest)
#pragma unroll
  for (int c = 0; c < 2; c++) {
    int L = c * 256 + tid;
    int row = L >> 3;
    int col = ((L & 7) ^ (row & 7)) * 8;
    GLOAD_LDS(Qg + (q0 + row) * 64 + col, QPs + L * 8);
    GLOAD_LDS(Kg + row * 64 + col,        &Ks[0][L * 8]);
    GLOAD_LDS(Vg + row * 1024 + col,      &VTs[0][L * 8]);
  }
  __syncthreads();
  bf16x8 qf[2];
  {
    const int qrow = w * 16 + (lane & 15);
    qf[0] = *(const bf16x8*)&QPs[qrow * 64 + ((g ^ r7) * 8)];
    qf[1] = *(const bf16x8*)&QPs[qrow * 64 + (((4 + g) ^ r7) * 8)];
  }

  const float SC = 0.125f * 1.44269504f;   // 1/sqrt(dh) * log2(e)
  float m_run[4], l_run[4];
  f32x4 acc_o[4] = {};
#pragma unroll
  for (int j = 0; j < 4; j++) { m_run[j] = -1e30f; l_run[j] = 0.0f; }

  int cur = 0;
  for (int kt = 0; kt < 16; kt++) {
    // issue next tile's stage first — drains under this tile's compute
    if (kt < 15) {
#pragma unroll
      for (int c = 0; c < 2; c++) {
        int L = c * 256 + tid;
        int row = L >> 3;
        int col = ((L & 7) ^ (row & 7)) * 8;
        GLOAD_LDS(Kg + ((kt + 1) * 64 + row) * 64 + col, &Ks[cur ^ 1][L * 8]);
        GLOAD_LDS(Vg + row * 1024 + (kt + 1) * 64 + col, &VTs[cur ^ 1][L * 8]);
      }
    }

    // ---- QK^T: wave computes 16 q-rows x 64 k-cols ----
    f32x4 sa[4] = {};
#pragma unroll
    for (int kk = 0; kk < 2; kk++) {
#pragma unroll
      for (int ni = 0; ni < 4; ni++) {
        int krow = ni * 16 + (lane & 15);
        bf16x8 kf = *(const bf16x8*)&Ks[cur][krow * 64 + (((kk * 4 + g) ^ r7) * 8)];
        sa[ni] = __builtin_amdgcn_mfma_f32_16x16x32_bf16(qf[kk], kf, sa[ni], 0, 0, 0);
      }
    }
    // ---- online softmax, exp2 domain; row-reduces via DPP (no DS ops) ----
    float mt[4], alpha[4], rs[4];
#pragma unroll
    for (int j = 0; j < 4; j++) {
      mt[j] = rowmax16(fmaxf(fmaxf(sa[0][j], sa[1][j]), fmaxf(sa[2][j], sa[3][j])));
      float mn = fmaxf(m_run[j], mt[j] * SC);
      alpha[j] = __builtin_amdgcn_exp2f(m_run[j] - mn);
      m_run[j] = mn;
      rs[j] = 0.0f;
    }
#pragma unroll
    for (int ni = 0; ni < 4; ni++) {
      int col = ni * 16 + (lane & 15);
#pragma unroll
      for (int j = 0; j < 4; j++) {
        int row = w * 16 + g * 4 + j;
        float p = __builtin_amdgcn_exp2f(sa[ni][j] * SC - m_run[j]);
        rs[j] += p;
        QPs[row * 64 + (col ^ ((row & 7) << 3))] = (short)f2bf(p);
      }
    }
#pragma unroll
    for (int j = 0; j < 4; j++) {
      rs[j] = rowsum16(rs[j]);
      l_run[j] = l_run[j] * alpha[j] + rs[j];
    }
#pragma unroll
    for (int di = 0; di < 4; di++)
#pragma unroll
      for (int j = 0; j < 4; j++)
        acc_o[di][j] *= alpha[j];
    // ---- PV: O[16q][64d] += P[16q][64k] * V[64k][64d] (V^T in LDS) ----
#pragma unroll
    for (int kk = 0; kk < 2; kk++) {
      int prow = w * 16 + (lane & 15);
      bf16x8 pf = *(const bf16x8*)&QPs[prow * 64 + (((kk * 4 + g) ^ r7) * 8)];
#pragma unroll
      for (int di = 0; di < 4; di++) {
        int vrow = di * 16 + (lane & 15);
        bf16x8 vf = *(const bf16x8*)&VTs[cur][vrow * 64 + (((kk * 4 + g) ^ r7) * 8)];
        acc_o[di] = __builtin_amdgcn_mfma_f32_16x16x32_bf16(pf, vf, acc_o[di], 0, 0, 0);
      }
    }
    __syncthreads();   // drains vmcnt: next tile staged; buf[cur] free for reuse
    cur ^= 1;
  }

  // write O [b][s][h*64+d] bf16
#pragma unroll
  for (int di = 0; di < 4; di++) {
    int d = hh * 64 + di * 16 + (lane & 15);
#pragma unroll
    for (int j = 0; j < 4; j++) {
      int q = q0 + w * 16 + g * 4 + j;
      O[(bb * 1024 + q) * 1024 + d] = (short)f2bf(acc_o[di][j] / l_run[j]);
    }
  }
}

extern "C" void kernel_launch(void* const* d_in, const int* in_sizes, int n_in,
                              void* d_out, int out_size, void* d_ws, size_t ws_size,
                              hipStream_t stream)
{
  (void)in_sizes; (void)n_in; (void)out_size; (void)ws_size;
  const float* q    = (const float*)d_in[0];
  const float* k    = (const float*)d_in[1];
  const float* v    = (const float*)d_in[2];
  const float* Wq_w = (const float*)d_in[3];
  const float* Wq_b = (const float*)d_in[4];
  const float* Wo_w = (const float*)d_in[5];
  const float* Wo_b = (const float*)d_in[6];
  float* out = (float*)d_out;

  short* ws   = (short*)d_ws;
  short* Xbf  = ws;                 // [3*4096][1024] bf16 (q,k,v inputs; Wqb/Wob follow)
  short* Obf  = ws;                 // aliases Xbf (dead after proj GEMM)
  short* Wqb  = ws + 12582912;
  short* Wob  = ws + 13631488;
  short* qkv  = ws + 14680064;

  cvt_all<<<14336, 256, 0, stream>>>(q, k, v, Wq_w, Wo_w, ws);

  dim3 gp(8, 96);   // N/128=8, M/128=96  (q,k,v batched: same Wq per reference bug)
  gemm_bt<0><<<gp, 256, 0, stream>>>(Xbf, Wqb, Wq_b, qkv, nullptr);

  attn_kernel<<<1024, 256, 0, stream>>>(qkv, Obf);

  dim3 gf(8, 32);
  gemm_bt<1><<<gf, 256, 0, stream>>>(Obf, Wob, Wo_b, nullptr, out);
}

// Round 6
// 190.368 us; speedup vs baseline: 1.1063x; 1.0847x over previous
//
#include <hip/hip_runtime.h>
#include <stdint.h>

// B=4, S=1024, E=1024, H=16, dh=64
// ws layout (shorts): Xbf/Obf @0 (12.58M), Wqb @12582912 (1M), Wob @13631488 (1M),
//                     qkv @14680064 (12.58M: Q [B][H][S][64], K same +4M, V^T [B][H][64][S] +8M)

typedef __attribute__((ext_vector_type(8))) short bf16x8;
typedef __attribute__((ext_vector_type(4))) float f32x4;
typedef __attribute__((ext_vector_type(4))) short short4v;

#define GLOAD_LDS(gp, lp)                                                      \
  __builtin_amdgcn_global_load_lds(                                            \
      (__attribute__((address_space(1))) void*)(gp),                           \
      (__attribute__((address_space(3))) void*)(lp), 16, 0, 0)

__device__ __forceinline__ unsigned short f2bf(float f) {
  union { float f; unsigned u; } v; v.f = f;
  unsigned r = v.u + 0x7FFFu + ((v.u >> 16) & 1u);
  return (unsigned short)(r >> 16);
}
// cheap round-half-up for P values (nonneg, feeds MFMA; 1 VALU op vs 3)
__device__ __forceinline__ unsigned short f2bf_fast(float f) {
  union { float f; unsigned u; } v; v.f = f;
  return (unsigned short)((v.u + 0x8000u) >> 16);
}

// DPP row_ror:N within each 16-lane row — VALU cross-lane, no DS pipe.
template<int CTRL>
__device__ __forceinline__ float dpp_rr(float x) {
  union { float f; int i; } a, r;
  a.f = x;
  r.i = __builtin_amdgcn_update_dpp(0, a.i, CTRL, 0xf, 0xf, false);
  return r.f;
}
__device__ __forceinline__ float rowmax16(float x) {
  x = fmaxf(x, dpp_rr<0x121>(x));
  x = fmaxf(x, dpp_rr<0x122>(x));
  x = fmaxf(x, dpp_rr<0x124>(x));
  x = fmaxf(x, dpp_rr<0x128>(x));
  return x;
}

// ---------- fp32 -> bf16 convert: all 5 tensors in ONE launch --------------
__global__ void cvt_all(const float* __restrict__ q, const float* __restrict__ k,
                        const float* __restrict__ v, const float* __restrict__ wq,
                        const float* __restrict__ wo, short* __restrict__ dst) {
  int i = blockIdx.x * 256 + threadIdx.x;
  const float* src; int j;
  if (i < 1048576)      { src = q;  j = i; }
  else if (i < 2097152) { src = k;  j = i - 1048576; }
  else if (i < 3145728) { src = v;  j = i - 2097152; }
  else if (i < 3407872) { src = wq; j = i - 3145728; }
  else                  { src = wo; j = i - 3407872; }
  float4 f = reinterpret_cast<const float4*>(src)[j];
  short4v o;
  o.x = (short)f2bf(f.x); o.y = (short)f2bf(f.y);
  o.z = (short)f2bf(f.z); o.w = (short)f2bf(f.w);
  reinterpret_cast<short4v*>(dst)[i] = o;
}

// ---------------- bf16 GEMM  C = A[M,1024] * W[1024,1024]^T + bias ---------
template<int EPI>
__global__ __launch_bounds__(256, 2)
void gemm_bt(const short* __restrict__ A, const short* __restrict__ Bw,
             const float* __restrict__ bias,
             short* __restrict__ qkv, float* __restrict__ outf)
{
  __shared__ short As[128 * 64];
  __shared__ short Bs[128 * 64];
  const int tid  = threadIdx.x;
  const int lane = tid & 63;
  const int g    = lane >> 4;     // 16-lane group 0..3
  const int r7   = lane & 7;
  const int w    = tid >> 6;      // wave 0..3
  const int wm   = w >> 1, wn = w & 1;

  // XCD-aware bijective swizzle (nwg%8==0)
  const int orig = blockIdx.y * 8 + blockIdx.x;
  const int cpx  = (gridDim.x * gridDim.y) >> 3;
  const int t    = (orig & 7) * cpx + (orig >> 3);
  const int m0   = (t >> 3) * 128, n0 = (t & 7) * 128;

  f32x4 acc[4][4] = {};

  for (int k0 = 0; k0 < 1024; k0 += 64) {
#pragma unroll
    for (int c = 0; c < 4; c++) {
      int L   = c * 256 + tid;
      int row = L >> 3;
      int col = ((L & 7) ^ (row & 7)) * 8;
      GLOAD_LDS(A  + (m0 + row) * 1024 + k0 + col, As + L * 8);
      GLOAD_LDS(Bw + (n0 + row) * 1024 + k0 + col, Bs + L * 8);
    }
    __syncthreads();
#pragma unroll
    for (int kk = 0; kk < 2; kk++) {
      bf16x8 av[4], bv[4];
#pragma unroll
      for (int mi = 0; mi < 4; mi++) {
        int row = wm * 64 + mi * 16 + (lane & 15);
        av[mi] = *(const bf16x8*)&As[row * 64 + (((kk * 4 + g) ^ r7) * 8)];
      }
#pragma unroll
      for (int ni = 0; ni < 4; ni++) {
        int row = wn * 64 + ni * 16 + (lane & 15);
        bv[ni] = *(const bf16x8*)&Bs[row * 64 + (((kk * 4 + g) ^ r7) * 8)];
      }
#pragma unroll
      for (int mi = 0; mi < 4; mi++)
#pragma unroll
        for (int ni = 0; ni < 4; ni++)
          acc[mi][ni] = __builtin_amdgcn_mfma_f32_16x16x32_bf16(av[mi], bv[ni], acc[mi][ni], 0, 0, 0);
    }
    __syncthreads();
  }

  if (EPI == 0) {
    const int inp = m0 >> 12;  // 0=q,1=k,2=v (block never straddles inputs)
#pragma unroll
    for (int mi = 0; mi < 4; mi++) {
#pragma unroll
      for (int ni = 0; ni < 4; ni++) {
        const int coll = n0 + wn * 64 + ni * 16 + (lane & 15);
        const float bv = bias[coll];
        const int rbase = m0 + wm * 64 + mi * 16 + (lane >> 4) * 4;
        const int hh = coll >> 6, d = coll & 63;
        if (inp < 2) {
#pragma unroll
          for (int j = 0; j < 4; j++) {
            int rowl = rbase + j;
            int bb = (rowl >> 10) & 3, s = rowl & 1023;
            qkv[(((inp * 4 + bb) * 16 + hh) * 1024 + s) * 64 + d] =
                (short)f2bf(acc[mi][ni][j] + bv);
          }
        } else {
          int bb = (rbase >> 10) & 3, s0 = rbase & 1023;
          short4v o;
          o.x = (short)f2bf(acc[mi][ni][0] + bv);
          o.y = (short)f2bf(acc[mi][ni][1] + bv);
          o.z = (short)f2bf(acc[mi][ni][2] + bv);
          o.w = (short)f2bf(acc[mi][ni][3] + bv);
          *(short4v*)&qkv[8 * 1024 * 1024 + ((bb * 16 + hh) * 64 + d) * 1024 + s0] = o;
        }
      }
    }
  } else {
#pragma unroll
    for (int mi = 0; mi < 4; mi++) {
#pragma unroll
      for (int ni = 0; ni < 4; ni++) {
        const int coll = n0 + wn * 64 + ni * 16 + (lane & 15);
        const float bv = bias[coll];
        const int rbase = m0 + wm * 64 + mi * 16 + (lane >> 4) * 4;
#pragma unroll
        for (int j = 0; j < 4; j++)
          outf[(rbase + j) * 1024 + coll] = acc[mi][ni][j] + bv;
      }
    }
  }
}

// ------- flash attention, 2-phase double-buffered: 1 block = (b,h,64 q) ----
__global__ __launch_bounds__(256, 2)
void attn_kernel(const short* __restrict__ qkv, short* __restrict__ O)
{
  __shared__ short Ks[2][64 * 64];
  __shared__ short VTs[2][64 * 64];
  __shared__ short QPs[64 * 64];   // Q tile during hoist, then per-wave P rows

  const int tid  = threadIdx.x;
  const int lane = tid & 63;
  const int l15  = lane & 15;
  const int g    = lane >> 4, r7 = lane & 7;
  const int w    = tid >> 6;

  // XCD swizzle: each XCD owns 8 contiguous (b,h) K/V sets (2 MB -> L2-fits)
  const int t   = (blockIdx.x & 7) * 128 + (blockIdx.x >> 3);
  const int qt  = t & 15, hh = (t >> 4) & 15, bb = t >> 8;
  const int q0  = qt * 64;

  const short* Qg = qkv + (bb * 16 + hh) * 1024 * 64;                     // [1024][64]
  const short* Kg = qkv + 4 * 1024 * 1024 + (bb * 16 + hh) * 1024 * 64;   // [1024][64]
  const short* Vg = qkv + 8 * 1024 * 1024 + (bb * 16 + hh) * 64 * 1024;   // [64][1024]

  // prologue: stage Q tile + K/V tile 0 (swizzled source, linear LDS dest)
#pragma unroll
  for (int c = 0; c < 2; c++) {
    int L = c * 256 + tid;
    int row = L >> 3;
    int col = ((L & 7) ^ (row & 7)) * 8;
    GLOAD_LDS(Qg + (q0 + row) * 64 + col, QPs + L * 8);
    GLOAD_LDS(Kg + row * 64 + col,        &Ks[0][L * 8]);
    GLOAD_LDS(Vg + row * 1024 + col,      &VTs[0][L * 8]);
  }
  __syncthreads();
  bf16x8 qf[2];
  {
    const int qrow = w * 16 + l15;
    qf[0] = *(const bf16x8*)&QPs[qrow * 64 + ((g ^ r7) * 8)];
    qf[1] = *(const bf16x8*)&QPs[qrow * 64 + (((4 + g) ^ r7) * 8)];
  }
  // B-operand with bf16 1.0 in column 0 only: acc_l = P * ones_col -> row-sums
  bf16x8 vf_l = {};
  if (l15 == 0) {
#pragma unroll
    for (int x = 0; x < 8; x++) vf_l[x] = (short)0x3F80;
  }

  const float SC = 0.125f * 1.44269504f;   // 1/sqrt(dh) * log2(e)
  float m_run[4];
  f32x4 acc_l = {};
  f32x4 acc_o[4] = {};
#pragma unroll
  for (int j = 0; j < 4; j++) m_run[j] = -1e30f;

  int cur = 0;
  for (int kt = 0; kt < 16; kt++) {
    // issue next tile's stage first — drains under this tile's compute
    if (kt < 15) {
#pragma unroll
      for (int c = 0; c < 2; c++) {
        int L = c * 256 + tid;
        int row = L >> 3;
        int col = ((L & 7) ^ (row & 7)) * 8;
        GLOAD_LDS(Kg + ((kt + 1) * 64 + row) * 64 + col, &Ks[cur ^ 1][L * 8]);
        GLOAD_LDS(Vg + row * 1024 + (kt + 1) * 64 + col, &VTs[cur ^ 1][L * 8]);
      }
    }

    // ---- QK^T: wave computes 16 q-rows x 64 k-cols ----
    f32x4 sa[4] = {};
    __builtin_amdgcn_s_setprio(1);
#pragma unroll
    for (int kk = 0; kk < 2; kk++) {
#pragma unroll
      for (int ni = 0; ni < 4; ni++) {
        int krow = ni * 16 + l15;
        bf16x8 kf = *(const bf16x8*)&Ks[cur][krow * 64 + (((kk * 4 + g) ^ r7) * 8)];
        sa[ni] = __builtin_amdgcn_mfma_f32_16x16x32_bf16(qf[kk], kf, sa[ni], 0, 0, 0);
      }
    }
    __builtin_amdgcn_s_setprio(0);

    // ---- online softmax, exp2 domain, defer-max (THR=8 in log2 units) ----
    float mtl[4];
#pragma unroll
    for (int j = 0; j < 4; j++)
      mtl[j] = fmaxf(fmaxf(sa[0][j], sa[1][j]), fmaxf(sa[2][j], sa[3][j])) * SC;
    float nd = fmaxf(fmaxf(mtl[0] - m_run[0], mtl[1] - m_run[1]),
                     fmaxf(mtl[2] - m_run[2], mtl[3] - m_run[3]));
    if (__any(nd > 8.0f)) {   // rare after tile 0: scores are small-variance
#pragma unroll
      for (int j = 0; j < 4; j++) {
        float mt = rowmax16(mtl[j]);
        float mn = fmaxf(m_run[j], mt);
        float alpha = __builtin_amdgcn_exp2f(m_run[j] - mn);
        m_run[j] = mn;
        acc_l[j] *= alpha;
#pragma unroll
        for (int di = 0; di < 4; di++) acc_o[di][j] *= alpha;
      }
    }
#pragma unroll
    for (int ni = 0; ni < 4; ni++) {
      int col = ni * 16 + l15;
#pragma unroll
      for (int j = 0; j < 4; j++) {
        int row = w * 16 + g * 4 + j;
        float p = __builtin_amdgcn_exp2f(sa[ni][j] * SC - m_run[j]);
        QPs[row * 64 + (col ^ ((row & 7) << 3))] = (short)f2bf_fast(p);
      }
    }
    // ---- PV: O[16q][64d] += P[16q][64k] * V[64k][64d]; l via ones-col ----
    __builtin_amdgcn_s_setprio(1);
#pragma unroll
    for (int kk = 0; kk < 2; kk++) {
      int prow = w * 16 + l15;
      bf16x8 pf = *(const bf16x8*)&QPs[prow * 64 + (((kk * 4 + g) ^ r7) * 8)];
      acc_l = __builtin_amdgcn_mfma_f32_16x16x32_bf16(pf, vf_l, acc_l, 0, 0, 0);
#pragma unroll
      for (int di = 0; di < 4; di++) {
        int vrow = di * 16 + l15;
        bf16x8 vf = *(const bf16x8*)&VTs[cur][vrow * 64 + (((kk * 4 + g) ^ r7) * 8)];
        acc_o[di] = __builtin_amdgcn_mfma_f32_16x16x32_bf16(pf, vf, acc_o[di], 0, 0, 0);
      }
    }
    __builtin_amdgcn_s_setprio(0);
    __syncthreads();   // drains vmcnt: next tile staged; buf[cur] free for reuse
    cur ^= 1;
  }

  // l lives in C-col 0 (lanes l15==0, reg j = row g*4+j): broadcast + invert
  float linv[4];
#pragma unroll
  for (int j = 0; j < 4; j++) {
    float lv = __shfl(acc_l[j], lane & 48);   // src lane g*16+0
    linv[j] = 1.0f / lv;
  }

  // write O [b][s][h*64+d] bf16
#pragma unroll
  for (int di = 0; di < 4; di++) {
    int d = hh * 64 + di * 16 + l15;
#pragma unroll
    for (int j = 0; j < 4; j++) {
      int q = q0 + w * 16 + g * 4 + j;
      O[(bb * 1024 + q) * 1024 + d] = (short)f2bf(acc_o[di][j] * linv[j]);
    }
  }
}

extern "C" void kernel_launch(void* const* d_in, const int* in_sizes, int n_in,
                              void* d_out, int out_size, void* d_ws, size_t ws_size,
                              hipStream_t stream)
{
  (void)in_sizes; (void)n_in; (void)out_size; (void)ws_size;
  const float* q    = (const float*)d_in[0];
  const float* k    = (const float*)d_in[1];
  const float* v    = (const float*)d_in[2];
  const float* Wq_w = (const float*)d_in[3];
  const float* Wq_b = (const float*)d_in[4];
  const float* Wo_w = (const float*)d_in[5];
  const float* Wo_b = (const float*)d_in[6];
  float* out = (float*)d_out;

  short* ws   = (short*)d_ws;
  short* Xbf  = ws;                 // [3*4096][1024] bf16 (q,k,v inputs; Wqb/Wob follow)
  short* Obf  = ws;                 // aliases Xbf (dead after proj GEMM)
  short* Wqb  = ws + 12582912;
  short* Wob  = ws + 13631488;
  short* qkv  = ws + 14680064;

  cvt_all<<<14336, 256, 0, stream>>>(q, k, v, Wq_w, Wo_w, ws);

  dim3 gp(8, 96);   // N/128=8, M/128=96  (q,k,v batched: same Wq per reference bug)
  gemm_bt<0><<<gp, 256, 0, stream>>>(Xbf, Wqb, Wq_b, qkv, nullptr);

  attn_kernel<<<1024, 256, 0, stream>>>(qkv, Obf);

  dim3 gf(8, 32);
  gemm_bt<1><<<gf, 256, 0, stream>>>(Obf, Wob, Wo_b, nullptr, out);
}